// Round 1
// baseline (819.781 us; speedup 1.0000x reference)
//
#include <hip/hip_runtime.h>
#include <stdint.h>

// ---------------------------------------------------------------------------
// GAT bot detector, 2-layer, N=50000 E=800000 IN=256 HID=128 HEADS=4.
// Pipeline: CSR build -> split-bf16 MFMA GEMM1 -> attn coef -> agg1 (writes
// h as bf16 hi/lo) -> split-bf16 GEMM2 -> attn coef -> agg2+classifier.
// ---------------------------------------------------------------------------

typedef __bf16 bf16_t;
typedef bf16_t bf16x8 __attribute__((ext_vector_type(8)));
typedef bf16_t bf16x4 __attribute__((ext_vector_type(4)));
typedef bf16_t bf16x2 __attribute__((ext_vector_type(2)));
typedef float f32x4 __attribute__((ext_vector_type(4)));

__device__ __forceinline__ void async_copy16(const bf16_t* g, bf16_t* l) {
  __builtin_amdgcn_global_load_lds(
      (const __attribute__((address_space(1))) void*)g,
      (__attribute__((address_space(3))) void*)l,
      16, 0, 0);
}

// --------------------------- CSR construction ------------------------------

// edge_index may be int32 (jax default) or int64 (if x64 enabled). Detect:
// for int64 little-endian, every odd 32-bit word of the buffer is 0.
__global__ void detect_i64_kernel(const int* __restrict__ ei, int* __restrict__ flag) {
  if (threadIdx.x == 0 && blockIdx.x == 0) {
    int nz = 0;
    for (int i = 0; i < 256; ++i) nz |= ei[2 * i + 1];
    *flag = (nz == 0) ? 1 : 0;
  }
}

__global__ void hist_kernel(const int* __restrict__ ei, int E, int N,
                            const int* __restrict__ flagp, int* __restrict__ deg) {
  int idx = blockIdx.x * blockDim.x + threadIdx.x;
  int EA = E + N;
  if (idx >= EA) return;
  int dst;
  if (idx < E) {
    dst = (*flagp) ? ei[2 * ((size_t)E + idx)] : ei[(size_t)E + idx];
  } else {
    dst = idx - E;  // self loop
  }
  if ((unsigned)dst >= (unsigned)N) return;
  atomicAdd(&deg[dst], 1);
}

__global__ __launch_bounds__(1024) void scan_kernel(const int* __restrict__ deg,
                                                    int* __restrict__ row_ptr,
                                                    int* __restrict__ cursor, int n) {
  __shared__ int sdata[1024];
  __shared__ int s_running;
  const int t = threadIdx.x;
  if (t == 0) { s_running = 0; row_ptr[0] = 0; }
  __syncthreads();
  for (int base = 0; base < n; base += 1024) {
    int i = base + t;
    int x = (i < n) ? deg[i] : 0;
    sdata[t] = x;
    __syncthreads();
    for (int off = 1; off < 1024; off <<= 1) {
      int v = (t >= off) ? sdata[t - off] : 0;
      __syncthreads();
      sdata[t] += v;
      __syncthreads();
    }
    int incl = sdata[t];
    int run = s_running;
    if (i < n) {
      row_ptr[i + 1] = run + incl;
      cursor[i] = run + incl - x;  // exclusive = start of bucket
    }
    __syncthreads();
    if (t == 1023) s_running = run + sdata[1023];
    __syncthreads();
  }
}

__global__ void scatter_kernel(const int* __restrict__ ei, int E, int N,
                               const int* __restrict__ flagp,
                               int* __restrict__ cursor, int* __restrict__ csr) {
  int idx = blockIdx.x * blockDim.x + threadIdx.x;
  int EA = E + N;
  if (idx >= EA) return;
  int src, dst;
  if (idx < E) {
    if (*flagp) { src = ei[2 * (size_t)idx]; dst = ei[2 * ((size_t)E + idx)]; }
    else        { src = ei[(size_t)idx];     dst = ei[(size_t)E + idx]; }
  } else {
    src = dst = idx - E;
  }
  if ((unsigned)dst >= (unsigned)N || (unsigned)src >= (unsigned)N) return;
  int pos = atomicAdd(&cursor[dst], 1);
  csr[pos] = src;
}

// --------------------- f32 -> bf16 hi/lo split convert ---------------------
// dst row layout: [0:cols) = hi, [cols:2*cols) = lo. Pad rows (>= srcRows) = 0.
__global__ void split_convert_kernel(const float* __restrict__ src, bf16_t* __restrict__ dst,
                                     int srcRows, int dstRows, int cols, int gshift) {
  int idx = blockIdx.x * blockDim.x + threadIdx.x;
  int total = dstRows << gshift;
  if (idx >= total) return;
  int row = idx >> gshift;
  int gi = idx & ((1 << gshift) - 1);
  int col = gi * 4;
  float4 v = make_float4(0.f, 0.f, 0.f, 0.f);
  if (row < srcRows) v = *(const float4*)&src[(size_t)row * cols + col];
  float vv[4] = {v.x, v.y, v.z, v.w};
  bf16x4 hi, lo;
#pragma unroll
  for (int k = 0; k < 4; ++k) {
    bf16_t h = (bf16_t)vv[k];
    hi[k] = h;
    lo[k] = (bf16_t)(vv[k] - (float)h);
  }
  size_t b = (size_t)row * (2 * cols) + col;
  *(bf16x4*)&dst[b] = hi;
  *(bf16x4*)&dst[b + cols] = lo;
}

// --------------------------- split-bf16 GEMM -------------------------------
// C[M,Ncols] = A * B^T over virtual K = 3*Ks/2:
//   A' col c -> A storage col (c & (Ks-1))      (A = [hi | lo], hi reused)
//   B' col c -> B storage col (c < Ks/2 ? c : c - Ks/2)  (B = [hi | lo])
// giving hi*hi + lo*hi + hi*lo. LDS chunks (16B) XOR-swizzled:
// chunk (r,c) lives at slot r*4 + (c ^ ((r>>1)&3)) to spread ds_read_b128 banks.
template <int BM, int TPB>
__global__ __launch_bounds__(TPB) void gemm_split_kernel(
    const bf16_t* __restrict__ A, const bf16_t* __restrict__ Bm, float* __restrict__ C,
    int Ks, int KV, int Ncols) {
  __shared__ bf16_t lA[BM * 32];
  __shared__ bf16_t lB[128 * 32];
  const int tid = threadIdx.x;
  const int w = tid >> 6, lane = tid & 63;
  const int wm = w >> 1, wn = w & 1;
  const int rowBase = blockIdx.y * BM;
  const int colBase = blockIdx.x * 128;
  const int lrow = lane & 15, lk = lane >> 4;
  f32x4 acc[4][4];
#pragma unroll
  for (int i = 0; i < 4; ++i)
#pragma unroll
    for (int j = 0; j < 4; ++j) acc[i][j] = (f32x4){0.f, 0.f, 0.f, 0.f};

  for (int kv = 0; kv < KV; kv += 32) {
    const int aCol = kv & (Ks - 1);
    const int bCol = (kv < (Ks >> 1)) ? kv : kv - (Ks >> 1);
#pragma unroll
    for (int s = 0; s < (BM * 4) / TPB; ++s) {
      int q = s * TPB + tid;
      int r = q >> 2;
      int cs = (q & 3) ^ ((r >> 1) & 3);
      async_copy16(A + (size_t)(rowBase + r) * Ks + aCol + cs * 8,
                   &lA[(s * TPB + w * 64) * 8]);
    }
#pragma unroll
    for (int s = 0; s < 512 / TPB; ++s) {
      int q = s * TPB + tid;
      int r = q >> 2;
      int cs = (q & 3) ^ ((r >> 1) & 3);
      async_copy16(Bm + (size_t)(colBase + r) * Ks + bCol + cs * 8,
                   &lB[(s * TPB + w * 64) * 8]);
    }
    __syncthreads();  // compiler drains vmcnt before s_barrier
    bf16x8 aF[4], bF[4];
#pragma unroll
    for (int i = 0; i < 4; ++i) {
      int ra = wm * 64 + i * 16 + lrow;
      aF[i] = *(const bf16x8*)&lA[(ra * 4 + (lk ^ ((ra >> 1) & 3))) * 8];
      int rb = wn * 64 + i * 16 + lrow;
      bF[i] = *(const bf16x8*)&lB[(rb * 4 + (lk ^ ((rb >> 1) & 3))) * 8];
    }
#pragma unroll
    for (int i = 0; i < 4; ++i)
#pragma unroll
      for (int j = 0; j < 4; ++j)
        acc[i][j] = __builtin_amdgcn_mfma_f32_16x16x32_bf16(aF[i], bF[j], acc[i][j], 0, 0, 0);
    __syncthreads();
  }
  // C/D layout: col = lane&15, row = (lane>>4)*4 + reg  (HW-verified, m89/m91)
#pragma unroll
  for (int i = 0; i < 4; ++i) {
    int row0 = rowBase + wm * 64 + i * 16 + lk * 4;
#pragma unroll
    for (int j = 0; j < 4; ++j) {
      int col = colBase + wn * 64 + j * 16 + lrow;
#pragma unroll
      for (int rr = 0; rr < 4; ++rr)
        C[(size_t)(row0 + rr) * Ncols + col] = acc[i][j][rr];
    }
  }
}

// ------------------- attention coefficients a_src / a_dst ------------------
// one wave per (node, head); xw row layout [N, H*128] so row index == wg.
__global__ __launch_bounds__(256) void attn_coef_kernel(
    const float* __restrict__ xw, const float* __restrict__ attS,
    const float* __restrict__ attD, float* __restrict__ aS, float* __restrict__ aD,
    int NH, int H) {
  int wg = blockIdx.x * 4 + (threadIdx.x >> 6);
  int lane = threadIdx.x & 63;
  if (wg >= NH) return;
  int h = wg & (H - 1);
  const float2 v = *(const float2*)&xw[(size_t)wg * 128 + lane * 2];
  const float2 s2 = *(const float2*)&attS[h * 128 + lane * 2];
  const float2 d2 = *(const float2*)&attD[h * 128 + lane * 2];
  float ps = v.x * s2.x + v.y * s2.y;
  float pd = v.x * d2.x + v.y * d2.y;
#pragma unroll
  for (int off = 32; off; off >>= 1) {
    ps += __shfl_xor(ps, off);
    pd += __shfl_xor(pd, off);
  }
  if (lane == 0) { aS[wg] = ps; aD[wg] = pd; }
}

// --------------------- layer-1 aggregation (per dst) -----------------------
// block = 4 waves = 4 heads, one dst node per block. Softmax without max
// subtraction (|e| <~ 10, exp safe in f32). Epilogue: elu(acc + b1) written
// as bf16 hi/lo into GEMM2's A operand.
__global__ __launch_bounds__(256) void agg1_kernel(
    const int* __restrict__ row_ptr, const int* __restrict__ csr,
    const float* __restrict__ aS, const float* __restrict__ aD,
    const float* __restrict__ xw, const float* __restrict__ bias,
    bf16_t* __restrict__ A2) {
  const int dst = blockIdx.x;
  const int h = threadIdx.x >> 6, lane = threadIdx.x & 63;
  const int beg = row_ptr[dst], end = row_ptr[dst + 1];
  const float a_d = aD[dst * 4 + h];
  float den = 0.f;
  for (int i = beg + lane; i < end; i += 64) {
    int s = csr[i];
    float e = aS[s * 4 + h] + a_d;
    e = (e > 0.f) ? e : 0.2f * e;
    den += __expf(e);
  }
#pragma unroll
  for (int off = 32; off; off >>= 1) den += __shfl_xor(den, off);
  const float inv = 1.f / den;
  float accx = 0.f, accy = 0.f;
  for (int base = beg; base < end; base += 64) {
    int i = base + lane;
    float wv = 0.f;
    int s = 0;
    if (i < end) {
      s = csr[i];
      float e = aS[s * 4 + h] + a_d;
      e = (e > 0.f) ? e : 0.2f * e;
      wv = __expf(e);
    }
    int m = end - base;
    if (m > 64) m = 64;
    for (int j = 0; j < m; ++j) {
      float alpha = __shfl(wv, j) * inv;
      int sj = __shfl(s, j);
      const float2 v = *(const float2*)&xw[(size_t)sj * 512 + h * 128 + lane * 2];
      accx = fmaf(alpha, v.x, accx);
      accy = fmaf(alpha, v.y, accy);
    }
  }
  const int c = h * 128 + lane * 2;
  float v0 = accx + bias[c], v1 = accy + bias[c + 1];
  v0 = (v0 > 0.f) ? v0 : (__expf(v0) - 1.f);
  v1 = (v1 > 0.f) ? v1 : (__expf(v1) - 1.f);
  bf16_t h0 = (bf16_t)v0, h1 = (bf16_t)v1;
  bf16x2 hi = {h0, h1};
  bf16x2 lo = {(bf16_t)(v0 - (float)h0), (bf16_t)(v1 - (float)h1)};
  *(bf16x2*)&A2[(size_t)dst * 1024 + c] = hi;
  *(bf16x2*)&A2[(size_t)dst * 1024 + 512 + c] = lo;
}

// ------------- layer-2 aggregation + ELU + fused classifier ----------------
// one wave per dst (H=1, C=128); block = 4 dst.
__global__ __launch_bounds__(256) void agg2_kernel(
    const int* __restrict__ row_ptr, const int* __restrict__ csr,
    const float* __restrict__ aS, const float* __restrict__ aD,
    const float* __restrict__ xw2, const float* __restrict__ b2,
    const float* __restrict__ Wc, const float* __restrict__ bc,
    float* __restrict__ out, int n) {
  const int dst = blockIdx.x * 4 + (threadIdx.x >> 6);
  const int lane = threadIdx.x & 63;
  if (dst >= n) return;
  const int beg = row_ptr[dst], end = row_ptr[dst + 1];
  const float a_d = aD[dst];
  float den = 0.f;
  for (int i = beg + lane; i < end; i += 64) {
    int s = csr[i];
    float e = aS[s] + a_d;
    e = (e > 0.f) ? e : 0.2f * e;
    den += __expf(e);
  }
#pragma unroll
  for (int off = 32; off; off >>= 1) den += __shfl_xor(den, off);
  const float inv = 1.f / den;
  float accx = 0.f, accy = 0.f;
  for (int base = beg; base < end; base += 64) {
    int i = base + lane;
    float wv = 0.f;
    int s = 0;
    if (i < end) {
      s = csr[i];
      float e = aS[s] + a_d;
      e = (e > 0.f) ? e : 0.2f * e;
      wv = __expf(e);
    }
    int m = end - base;
    if (m > 64) m = 64;
    for (int j = 0; j < m; ++j) {
      float alpha = __shfl(wv, j) * inv;
      int sj = __shfl(s, j);
      const float2 v = *(const float2*)&xw2[(size_t)sj * 128 + lane * 2];
      accx = fmaf(alpha, v.x, accx);
      accy = fmaf(alpha, v.y, accy);
    }
  }
  const int c = lane * 2;
  float v0 = accx + b2[c], v1 = accy + b2[c + 1];
  v0 = (v0 > 0.f) ? v0 : (__expf(v0) - 1.f);
  v1 = (v1 > 0.f) ? v1 : (__expf(v1) - 1.f);
  const float2 w0 = *(const float2*)&Wc[c];
  const float2 w1 = *(const float2*)&Wc[128 + c];
  float l0 = v0 * w0.x + v1 * w0.y;
  float l1 = v0 * w1.x + v1 * w1.y;
#pragma unroll
  for (int off = 32; off; off >>= 1) {
    l0 += __shfl_xor(l0, off);
    l1 += __shfl_xor(l1, off);
  }
  if (lane == 0) {
    out[dst * 2] = l0 + bc[0];
    out[dst * 2 + 1] = l1 + bc[1];
  }
}

// ---------------------------------------------------------------------------

extern "C" void kernel_launch(void* const* d_in, const int* in_sizes, int n_in,
                              void* d_out, int out_size, void* d_ws, size_t ws_size,
                              hipStream_t stream) {
  const float* x     = (const float*)d_in[0];
  const int*   ei    = (const int*)d_in[1];
  const float* W1    = (const float*)d_in[2];
  const float* att1s = (const float*)d_in[3];
  const float* att1d = (const float*)d_in[4];
  const float* b1    = (const float*)d_in[5];
  const float* W2    = (const float*)d_in[6];
  const float* att2s = (const float*)d_in[7];
  const float* att2d = (const float*)d_in[8];
  const float* b2    = (const float*)d_in[9];
  const float* Wc    = (const float*)d_in[10];
  const float* bc    = (const float*)d_in[11];
  float* out = (float*)d_out;

  const int N = in_sizes[0] / 256;
  const int E = in_sizes[1] / 2;
  const int EA = E + N;
  const int Mpad = (N + 127) & ~127;

  char* base = (char*)d_ws;
  size_t off = 0;
  auto alloc = [&](size_t bytes) -> char* {
    char* p = base + off;
    off = (off + bytes + 255) & ~(size_t)255;
    return p;
  };
  // Arena 0: A2 [Mpad,1024] bf16. A1 [Mpad,512] bf16 and B1 [512,512] bf16
  // alias its head: both are dead before agg1 writes A2 (rows < N), and the
  // A2 pad-row memset only touches bytes beyond A1+B1.
  char* arena0 = alloc((size_t)Mpad * 1024 * sizeof(bf16_t));
  bf16_t* A2 = (bf16_t*)arena0;
  bf16_t* A1 = (bf16_t*)arena0;
  bf16_t* B1 = (bf16_t*)(arena0 + (size_t)Mpad * 512 * sizeof(bf16_t));
  // Arena 1: xw1 [Mpad,512] f32; xw2 [Mpad,128] f32 aliases (xw1 dead after agg1).
  char* arena1 = alloc((size_t)Mpad * 512 * sizeof(float));
  float* xw1 = (float*)arena1;
  float* xw2 = (float*)arena1;
  float* aS1 = (float*)alloc((size_t)N * 4 * sizeof(float));
  float* aD1 = (float*)alloc((size_t)N * 4 * sizeof(float));
  bf16_t* B2 = (bf16_t*)alloc((size_t)128 * 1024 * sizeof(bf16_t));
  float* aS2 = (float*)alloc((size_t)N * sizeof(float));
  float* aD2 = (float*)alloc((size_t)N * sizeof(float));
  int* deg     = (int*)alloc((size_t)N * sizeof(int));
  int* row_ptr = (int*)alloc((size_t)(N + 1) * sizeof(int));
  int* cursor  = (int*)alloc((size_t)N * sizeof(int));
  int* csr     = (int*)alloc((size_t)EA * sizeof(int));
  int* flag    = (int*)alloc(256);
  (void)n_in; (void)out_size; (void)ws_size;

  hipMemsetAsync(deg, 0, (size_t)N * sizeof(int), stream);
  if (Mpad > N)
    hipMemsetAsync(A2 + (size_t)N * 1024, 0, (size_t)(Mpad - N) * 1024 * sizeof(bf16_t), stream);

  detect_i64_kernel<<<1, 64, 0, stream>>>(ei, flag);
  hist_kernel<<<(EA + 255) / 256, 256, 0, stream>>>(ei, E, N, flag, deg);
  scan_kernel<<<1, 1024, 0, stream>>>(deg, row_ptr, cursor, N);
  scatter_kernel<<<(EA + 255) / 256, 256, 0, stream>>>(ei, E, N, flag, cursor, csr);

  split_convert_kernel<<<(Mpad * 64 + 255) / 256, 256, 0, stream>>>(x, A1, N, Mpad, 256, 6);
  split_convert_kernel<<<(512 * 64 + 255) / 256, 256, 0, stream>>>(W1, B1, 512, 512, 256, 6);
  split_convert_kernel<<<(128 * 128 + 255) / 256, 256, 0, stream>>>(W2, B2, 128, 128, 512, 7);

  dim3 g1(4, Mpad / 128);
  gemm_split_kernel<128, 256><<<g1, 256, 0, stream>>>(A1, B1, xw1, 512, 768, 512);
  attn_coef_kernel<<<N, 256, 0, stream>>>(xw1, att1s, att1d, aS1, aD1, N * 4, 4);
  agg1_kernel<<<N, 256, 0, stream>>>(row_ptr, csr, aS1, aD1, xw1, b1, A2);

  dim3 g2(1, Mpad / 64);
  gemm_split_kernel<64, 128><<<g2, 128, 0, stream>>>(A2, B2, xw2, 1024, 1536, 128);
  attn_coef_kernel<<<(N + 3) / 4, 256, 0, stream>>>(xw2, att2s, att2d, aS2, aD2, N, 1);
  agg2_kernel<<<(N + 3) / 4, 256, 0, stream>>>(row_ptr, csr, aS2, aD2, xw2, b2, Wc, bc, out, N);
}

// Round 3
// 686.404 us; speedup vs baseline: 1.1943x; 1.1943x over previous
//
#include <hip/hip_runtime.h>
#include <stdint.h>

// ---------------------------------------------------------------------------
// GAT bot detector, 2-layer, N=50000 E=800000 IN=256 HID=128 HEADS=4.
// Round 3: identical to round 2 EXCEPT GEMM staging uses synchronous vector
// loads + ds_write (no global_load_lds) — differential test for the
// post-timing divergence seen in round 2.
// ---------------------------------------------------------------------------

typedef _Float16 f16;
typedef f16 f16x8 __attribute__((ext_vector_type(8)));
typedef f16 f16x4 __attribute__((ext_vector_type(4)));
typedef f16 f16x2 __attribute__((ext_vector_type(2)));
typedef float f32x4 __attribute__((ext_vector_type(4)));

// --------------------------- CSR construction ------------------------------

__global__ void detect_i64_kernel(const int* __restrict__ ei, int* __restrict__ flag) {
  if (threadIdx.x == 0 && blockIdx.x == 0) {
    int nz = 0;
    for (int i = 0; i < 256; ++i) nz |= ei[2 * i + 1];
    *flag = (nz == 0) ? 1 : 0;
  }
}

__global__ void hist_kernel(const int* __restrict__ ei, int E, int N,
                            const int* __restrict__ flagp, int* __restrict__ deg) {
  int idx = blockIdx.x * blockDim.x + threadIdx.x;
  int EA = E + N;
  if (idx >= EA) return;
  int dst;
  if (idx < E) {
    dst = (*flagp) ? ei[2 * ((size_t)E + idx)] : ei[(size_t)E + idx];
  } else {
    dst = idx - E;  // self loop
  }
  if ((unsigned)dst >= (unsigned)N) return;
  atomicAdd(&deg[dst], 1);
}

__global__ __launch_bounds__(1024) void scan_kernel(const int* __restrict__ deg,
                                                    int* __restrict__ row_ptr,
                                                    int* __restrict__ cursor, int n) {
  __shared__ int sdata[1024];
  __shared__ int s_running;
  const int t = threadIdx.x;
  if (t == 0) { s_running = 0; row_ptr[0] = 0; }
  __syncthreads();
  for (int base = 0; base < n; base += 1024) {
    int i = base + t;
    int x = (i < n) ? deg[i] : 0;
    sdata[t] = x;
    __syncthreads();
    for (int off = 1; off < 1024; off <<= 1) {
      int v = (t >= off) ? sdata[t - off] : 0;
      __syncthreads();
      sdata[t] += v;
      __syncthreads();
    }
    int incl = sdata[t];
    int run = s_running;
    if (i < n) {
      row_ptr[i + 1] = run + incl;
      cursor[i] = run + incl - x;  // exclusive = start of bucket
    }
    __syncthreads();
    if (t == 1023) s_running = run + sdata[1023];
    __syncthreads();
  }
}

__global__ void scatter_kernel(const int* __restrict__ ei, int E, int N,
                               const int* __restrict__ flagp,
                               int* __restrict__ cursor, int* __restrict__ csr) {
  int idx = blockIdx.x * blockDim.x + threadIdx.x;
  int EA = E + N;
  if (idx >= EA) return;
  int src, dst;
  if (idx < E) {
    if (*flagp) { src = ei[2 * (size_t)idx]; dst = ei[2 * ((size_t)E + idx)]; }
    else        { src = ei[(size_t)idx];     dst = ei[(size_t)E + idx]; }
  } else {
    src = dst = idx - E;
  }
  if ((unsigned)dst >= (unsigned)N || (unsigned)src >= (unsigned)N) return;
  int pos = atomicAdd(&cursor[dst], 1);
  csr[pos] = src;
}

// --------------------------- f32 -> f16 convert ----------------------------
// Pad rows (>= srcRows) zeroed. gshift = log2(cols/4).
__global__ void cvt_f16_kernel(const float* __restrict__ src, f16* __restrict__ dst,
                               int srcRows, int dstRows, int cols, int gshift) {
  int idx = blockIdx.x * blockDim.x + threadIdx.x;
  int total = dstRows << gshift;
  if (idx >= total) return;
  int row = idx >> gshift;
  int col = (idx & ((1 << gshift) - 1)) * 4;
  float4 v = make_float4(0.f, 0.f, 0.f, 0.f);
  if (row < srcRows) v = *(const float4*)&src[(size_t)row * cols + col];
  f16x4 o = {(f16)v.x, (f16)v.y, (f16)v.z, (f16)v.w};
  *(f16x4*)&dst[(size_t)row * cols + col] = o;
}

// ------------------------------ f16 GEMM -----------------------------------
// C[M,Ncols] = A * B^T, A[M,K] f16, B[Ncols,K] f16, C f16.
// LDS 16B chunks XOR-swizzled: LDS slot r*4+c holds global chunk
// (r, c ^ ((r>>1)&3)); fragment read applies the same XOR to recover.
// Staging: synchronous global vector load -> ds_write (round-3 change).
template <int BM, int TPB>
__global__ __launch_bounds__(TPB) void gemm_f16_kernel(
    const f16* __restrict__ A, const f16* __restrict__ Bm, f16* __restrict__ C,
    int K, int Ncols) {
  __shared__ f16 lA[BM * 32];
  __shared__ f16 lB[128 * 32];
  const int tid = threadIdx.x;
  const int w = tid >> 6, lane = tid & 63;
  const int wm = w >> 1, wn = w & 1;
  const int rowBase = blockIdx.y * BM;
  const int colBase = blockIdx.x * 128;
  const int lrow = lane & 15, lk = lane >> 4;
  f32x4 acc[4][4];
#pragma unroll
  for (int i = 0; i < 4; ++i)
#pragma unroll
    for (int j = 0; j < 4; ++j) acc[i][j] = (f32x4){0.f, 0.f, 0.f, 0.f};

  for (int kv = 0; kv < K; kv += 32) {
    f16x8 stA[(BM * 4) / TPB], stB[512 / TPB];
#pragma unroll
    for (int s = 0; s < (BM * 4) / TPB; ++s) {
      int q = s * TPB + tid;
      int r = q >> 2;
      int cs = (q & 3) ^ ((r >> 1) & 3);
      stA[s] = *(const f16x8*)(A + (size_t)(rowBase + r) * K + kv + cs * 8);
    }
#pragma unroll
    for (int s = 0; s < 512 / TPB; ++s) {
      int q = s * TPB + tid;
      int r = q >> 2;
      int cs = (q & 3) ^ ((r >> 1) & 3);
      stB[s] = *(const f16x8*)(Bm + (size_t)(colBase + r) * K + kv + cs * 8);
    }
#pragma unroll
    for (int s = 0; s < (BM * 4) / TPB; ++s)
      *(f16x8*)&lA[(size_t)(s * TPB + tid) * 8] = stA[s];
#pragma unroll
    for (int s = 0; s < 512 / TPB; ++s)
      *(f16x8*)&lB[(size_t)(s * TPB + tid) * 8] = stB[s];
    __syncthreads();
    f16x8 aF[4], bF[4];
#pragma unroll
    for (int i = 0; i < 4; ++i) {
      int ra = wm * 64 + i * 16 + lrow;
      aF[i] = *(const f16x8*)&lA[(ra * 4 + (lk ^ ((ra >> 1) & 3))) * 8];
      int rb = wn * 64 + i * 16 + lrow;
      bF[i] = *(const f16x8*)&lB[(rb * 4 + (lk ^ ((rb >> 1) & 3))) * 8];
    }
#pragma unroll
    for (int i = 0; i < 4; ++i)
#pragma unroll
      for (int j = 0; j < 4; ++j)
        acc[i][j] = __builtin_amdgcn_mfma_f32_16x16x32_f16(aF[i], bF[j], acc[i][j], 0, 0, 0);
    __syncthreads();
  }
  // C/D layout: col = lane&15, row = (lane>>4)*4 + reg  (HW-verified)
#pragma unroll
  for (int i = 0; i < 4; ++i) {
    int row0 = rowBase + wm * 64 + i * 16 + lk * 4;
#pragma unroll
    for (int j = 0; j < 4; ++j) {
      int col = colBase + wn * 64 + j * 16 + lrow;
#pragma unroll
      for (int rr = 0; rr < 4; ++rr)
        C[(size_t)(row0 + rr) * Ncols + col] = (f16)acc[i][j][rr];
    }
  }
}

// ------------------- attention coefficients a_src / a_dst ------------------
// one wave per (node,head); xw row layout [NH, 128] f16.
__global__ __launch_bounds__(256) void attn_coef_kernel(
    const f16* __restrict__ xw, const float* __restrict__ attS,
    const float* __restrict__ attD, float* __restrict__ aS, float* __restrict__ aD,
    int NH, int H) {
  int wg = blockIdx.x * 4 + (threadIdx.x >> 6);
  int lane = threadIdx.x & 63;
  if (wg >= NH) return;
  int h = wg & (H - 1);
  const f16x2 v = *(const f16x2*)&xw[(size_t)wg * 128 + lane * 2];
  const float2 s2 = *(const float2*)&attS[h * 128 + lane * 2];
  const float2 d2 = *(const float2*)&attD[h * 128 + lane * 2];
  float ps = (float)v[0] * s2.x + (float)v[1] * s2.y;
  float pd = (float)v[0] * d2.x + (float)v[1] * d2.y;
#pragma unroll
  for (int off = 32; off; off >>= 1) {
    ps += __shfl_xor(ps, off);
    pd += __shfl_xor(pd, off);
  }
  if (lane == 0) { aS[wg] = ps; aD[wg] = pd; }
}

// --------------------- layer-1 aggregation (per dst) -----------------------
// block = 4 waves = 4 heads, one dst node per block. Softmax without max
// subtraction (|e| <~ 10). Epilogue: elu(acc + b1) -> f16 into GEMM2's A.
__global__ __launch_bounds__(256) void agg1_kernel(
    const int* __restrict__ row_ptr, const int* __restrict__ csr,
    const float* __restrict__ aS, const float* __restrict__ aD,
    const f16* __restrict__ xw, const float* __restrict__ bias,
    f16* __restrict__ A2) {
  const int dst = blockIdx.x;
  const int h = threadIdx.x >> 6, lane = threadIdx.x & 63;
  const int beg = row_ptr[dst], end = row_ptr[dst + 1];
  const float a_d = aD[dst * 4 + h];
  float den = 0.f;
  for (int i = beg + lane; i < end; i += 64) {
    int s = csr[i];
    float e = aS[s * 4 + h] + a_d;
    e = (e > 0.f) ? e : 0.2f * e;
    den += __expf(e);
  }
#pragma unroll
  for (int off = 32; off; off >>= 1) den += __shfl_xor(den, off);
  const float inv = 1.f / den;
  float accx = 0.f, accy = 0.f;
  for (int base = beg; base < end; base += 64) {
    int i = base + lane;
    float wv = 0.f;
    int s = 0;
    if (i < end) {
      s = csr[i];
      float e = aS[s * 4 + h] + a_d;
      e = (e > 0.f) ? e : 0.2f * e;
      wv = __expf(e);
    }
    int m = end - base;
    if (m > 64) m = 64;
    for (int j = 0; j < m; ++j) {
      float alpha = __shfl(wv, j) * inv;
      int sj = __shfl(s, j);
      const f16x2 v = *(const f16x2*)&xw[(size_t)sj * 512 + h * 128 + lane * 2];
      accx = fmaf(alpha, (float)v[0], accx);
      accy = fmaf(alpha, (float)v[1], accy);
    }
  }
  const int c = h * 128 + lane * 2;
  float v0 = accx + bias[c], v1 = accy + bias[c + 1];
  v0 = (v0 > 0.f) ? v0 : (__expf(v0) - 1.f);
  v1 = (v1 > 0.f) ? v1 : (__expf(v1) - 1.f);
  f16x2 o = {(f16)v0, (f16)v1};
  *(f16x2*)&A2[(size_t)dst * 512 + c] = o;
}

// ------------- layer-2 aggregation + ELU + fused classifier ----------------
// one wave per dst (H=1, C=128); block = 4 dst.
__global__ __launch_bounds__(256) void agg2_kernel(
    const int* __restrict__ row_ptr, const int* __restrict__ csr,
    const float* __restrict__ aS, const float* __restrict__ aD,
    const f16* __restrict__ xw2, const float* __restrict__ b2,
    const float* __restrict__ Wc, const float* __restrict__ bc,
    float* __restrict__ out, int n) {
  const int dst = blockIdx.x * 4 + (threadIdx.x >> 6);
  const int lane = threadIdx.x & 63;
  if (dst >= n) return;
  const int beg = row_ptr[dst], end = row_ptr[dst + 1];
  const float a_d = aD[dst];
  float den = 0.f;
  for (int i = beg + lane; i < end; i += 64) {
    int s = csr[i];
    float e = aS[s] + a_d;
    e = (e > 0.f) ? e : 0.2f * e;
    den += __expf(e);
  }
#pragma unroll
  for (int off = 32; off; off >>= 1) den += __shfl_xor(den, off);
  const float inv = 1.f / den;
  float accx = 0.f, accy = 0.f;
  for (int base = beg; base < end; base += 64) {
    int i = base + lane;
    float wv = 0.f;
    int s = 0;
    if (i < end) {
      s = csr[i];
      float e = aS[s] + a_d;
      e = (e > 0.f) ? e : 0.2f * e;
      wv = __expf(e);
    }
    int m = end - base;
    if (m > 64) m = 64;
    for (int j = 0; j < m; ++j) {
      float alpha = __shfl(wv, j) * inv;
      int sj = __shfl(s, j);
      const f16x2 v = *(const f16x2*)&xw2[(size_t)sj * 128 + lane * 2];
      accx = fmaf(alpha, (float)v[0], accx);
      accy = fmaf(alpha, (float)v[1], accy);
    }
  }
  const int c = lane * 2;
  float v0 = accx + b2[c], v1 = accy + b2[c + 1];
  v0 = (v0 > 0.f) ? v0 : (__expf(v0) - 1.f);
  v1 = (v1 > 0.f) ? v1 : (__expf(v1) - 1.f);
  const float2 w0 = *(const float2*)&Wc[c];
  const float2 w1 = *(const float2*)&Wc[128 + c];
  float l0 = v0 * w0.x + v1 * w0.y;
  float l1 = v0 * w1.x + v1 * w1.y;
#pragma unroll
  for (int off = 32; off; off >>= 1) {
    l0 += __shfl_xor(l0, off);
    l1 += __shfl_xor(l1, off);
  }
  if (lane == 0) {
    out[dst * 2] = l0 + bc[0];
    out[dst * 2 + 1] = l1 + bc[1];
  }
}

// ---------------------------------------------------------------------------

extern "C" void kernel_launch(void* const* d_in, const int* in_sizes, int n_in,
                              void* d_out, int out_size, void* d_ws, size_t ws_size,
                              hipStream_t stream) {
  const float* x     = (const float*)d_in[0];
  const int*   ei    = (const int*)d_in[1];
  const float* W1    = (const float*)d_in[2];
  const float* att1s = (const float*)d_in[3];
  const float* att1d = (const float*)d_in[4];
  const float* b1    = (const float*)d_in[5];
  const float* W2    = (const float*)d_in[6];
  const float* att2s = (const float*)d_in[7];
  const float* att2d = (const float*)d_in[8];
  const float* b2    = (const float*)d_in[9];
  const float* Wc    = (const float*)d_in[10];
  const float* bc    = (const float*)d_in[11];
  float* out = (float*)d_out;

  const int N = in_sizes[0] / 256;
  const int E = in_sizes[1] / 2;
  const int EA = E + N;
  const int Mpad = (N + 127) & ~127;

  char* base = (char*)d_ws;
  size_t off = 0;
  auto alloc = [&](size_t bytes) -> char* {
    char* p = base + off;
    off = (off + bytes + 255) & ~(size_t)255;
    return p;
  };
  f16* A1f  = (f16*)alloc((size_t)Mpad * 256 * sizeof(f16));   // x in f16
  f16* B1f  = (f16*)alloc((size_t)512 * 256 * sizeof(f16));    // W1 f16
  f16* xw1h = (f16*)alloc((size_t)Mpad * 512 * sizeof(f16));   // layer1 pre-agg
  f16* A2   = (f16*)alloc((size_t)Mpad * 512 * sizeof(f16));   // h = elu(agg1)
  f16* B2f  = (f16*)alloc((size_t)128 * 512 * sizeof(f16));    // W2 f16
  f16* xw2h = (f16*)alloc((size_t)Mpad * 128 * sizeof(f16));   // layer2 pre-agg
  float* aS1 = (float*)alloc((size_t)N * 4 * sizeof(float));
  float* aD1 = (float*)alloc((size_t)N * 4 * sizeof(float));
  float* aS2 = (float*)alloc((size_t)N * sizeof(float));
  float* aD2 = (float*)alloc((size_t)N * sizeof(float));
  int* deg     = (int*)alloc((size_t)N * sizeof(int));
  int* row_ptr = (int*)alloc((size_t)(N + 1) * sizeof(int));
  int* cursor  = (int*)alloc((size_t)N * sizeof(int));
  int* csr     = (int*)alloc((size_t)EA * sizeof(int));
  int* flag    = (int*)alloc(256);
  (void)n_in; (void)out_size; (void)ws_size;

  hipMemsetAsync(deg, 0, (size_t)N * sizeof(int), stream);
  if (Mpad > N)  // zero A2 pad rows so GEMM2 pad outputs stay finite
    hipMemsetAsync(A2 + (size_t)N * 512, 0, (size_t)(Mpad - N) * 512 * sizeof(f16), stream);

  detect_i64_kernel<<<1, 64, 0, stream>>>(ei, flag);
  hist_kernel<<<(EA + 255) / 256, 256, 0, stream>>>(ei, E, N, flag, deg);
  scan_kernel<<<1, 1024, 0, stream>>>(deg, row_ptr, cursor, N);
  scatter_kernel<<<(EA + 255) / 256, 256, 0, stream>>>(ei, E, N, flag, cursor, csr);

  cvt_f16_kernel<<<(Mpad * 64 + 255) / 256, 256, 0, stream>>>(x, A1f, N, Mpad, 256, 6);
  cvt_f16_kernel<<<(512 * 64 + 255) / 256, 256, 0, stream>>>(W1, B1f, 512, 512, 256, 6);
  cvt_f16_kernel<<<(128 * 128 + 255) / 256, 256, 0, stream>>>(W2, B2f, 128, 128, 512, 7);

  dim3 g1(4, Mpad / 128);
  gemm_f16_kernel<128, 256><<<g1, 256, 0, stream>>>(A1f, B1f, xw1h, 256, 512);
  attn_coef_kernel<<<N, 256, 0, stream>>>(xw1h, att1s, att1d, aS1, aD1, N * 4, 4);
  agg1_kernel<<<N, 256, 0, stream>>>(row_ptr, csr, aS1, aD1, xw1h, b1, A2);

  dim3 g2(1, Mpad / 64);
  gemm_f16_kernel<64, 128><<<g2, 128, 0, stream>>>(A2, B2f, xw2h, 512, 128);
  attn_coef_kernel<<<(N + 3) / 4, 256, 0, stream>>>(xw2h, att2s, att2d, aS2, aD2, N, 1);
  agg2_kernel<<<(N + 3) / 4, 256, 0, stream>>>(row_ptr, csr, aS2, aD2, xw2h, b2, Wc, bc, out, N);
}

// Round 4
// 484.315 us; speedup vs baseline: 1.6927x; 1.4173x over previous
//
#include <hip/hip_runtime.h>
#include <stdint.h>

// ---------------------------------------------------------------------------
// GAT bot detector, 2-layer, N=50000 E=800000 IN=256 HID=128 HEADS=4.
// Round 4: keep round-3 pipeline (sync-staged GEMMs — global_load_lds proved
// racy here); restructure agg1/agg2 for memory-level parallelism:
// 2 edges/iteration (32 lanes x f16x4 each) x 4-deep unroll = 8 gathers in
// flight per wave. Multi-block scan replaces the 1-CU monolithic scan.
// ---------------------------------------------------------------------------

typedef _Float16 f16;
typedef f16 f16x8 __attribute__((ext_vector_type(8)));
typedef f16 f16x4 __attribute__((ext_vector_type(4)));
typedef f16 f16x2 __attribute__((ext_vector_type(2)));
typedef float f32x4 __attribute__((ext_vector_type(4)));

// --------------------------- CSR construction ------------------------------

__global__ void detect_i64_kernel(const int* __restrict__ ei, int* __restrict__ flag) {
  if (threadIdx.x == 0 && blockIdx.x == 0) {
    int nz = 0;
    for (int i = 0; i < 256; ++i) nz |= ei[2 * i + 1];
    *flag = (nz == 0) ? 1 : 0;
  }
}

__global__ void hist_kernel(const int* __restrict__ ei, int E, int N,
                            const int* __restrict__ flagp, int* __restrict__ deg) {
  int idx = blockIdx.x * blockDim.x + threadIdx.x;
  int EA = E + N;
  if (idx >= EA) return;
  int dst;
  if (idx < E) {
    dst = (*flagp) ? ei[2 * ((size_t)E + idx)] : ei[(size_t)E + idx];
  } else {
    dst = idx - E;  // self loop
  }
  if ((unsigned)dst >= (unsigned)N) return;
  atomicAdd(&deg[dst], 1);
}

// 3-phase scan: per-block inclusive -> block-sums scan -> fixup.
__global__ __launch_bounds__(256) void scan1_kernel(const int* __restrict__ deg,
                                                    int* __restrict__ tmp,
                                                    int* __restrict__ bsum, int n) {
  __shared__ int sd[256];
  const int t = threadIdx.x;
  const int i = blockIdx.x * 256 + t;
  int x = (i < n) ? deg[i] : 0;
  sd[t] = x;
  __syncthreads();
  for (int off = 1; off < 256; off <<= 1) {
    int v = (t >= off) ? sd[t - off] : 0;
    __syncthreads();
    sd[t] += v;
    __syncthreads();
  }
  if (i < n) tmp[i] = sd[t];
  if (t == 255) bsum[blockIdx.x] = sd[255];
}

__global__ __launch_bounds__(256) void scan2_kernel(const int* __restrict__ bsum,
                                                    int* __restrict__ boff, int nb) {
  __shared__ int sd[256];
  const int t = threadIdx.x;
  int x = (t < nb) ? bsum[t] : 0;
  sd[t] = x;
  __syncthreads();
  for (int off = 1; off < 256; off <<= 1) {
    int v = (t >= off) ? sd[t - off] : 0;
    __syncthreads();
    sd[t] += v;
    __syncthreads();
  }
  if (t < nb) boff[t] = sd[t] - x;  // exclusive
}

__global__ void scan3_kernel(const int* __restrict__ deg, const int* __restrict__ tmp,
                             const int* __restrict__ boff, int* __restrict__ row_ptr,
                             int* __restrict__ cursor, int n) {
  int i = blockIdx.x * 256 + threadIdx.x;
  if (i >= n) return;
  int g = tmp[i] + boff[i >> 8];
  row_ptr[i + 1] = g;
  cursor[i] = g - deg[i];
  if (i == 0) row_ptr[0] = 0;
}

__global__ void scatter_kernel(const int* __restrict__ ei, int E, int N,
                               const int* __restrict__ flagp,
                               int* __restrict__ cursor, int* __restrict__ csr) {
  int idx = blockIdx.x * blockDim.x + threadIdx.x;
  int EA = E + N;
  if (idx >= EA) return;
  int src, dst;
  if (idx < E) {
    if (*flagp) { src = ei[2 * (size_t)idx]; dst = ei[2 * ((size_t)E + idx)]; }
    else        { src = ei[(size_t)idx];     dst = ei[(size_t)E + idx]; }
  } else {
    src = dst = idx - E;
  }
  if ((unsigned)dst >= (unsigned)N || (unsigned)src >= (unsigned)N) return;
  int pos = atomicAdd(&cursor[dst], 1);
  csr[pos] = src;
}

// --------------------------- f32 -> f16 convert ----------------------------
__global__ void cvt_f16_kernel(const float* __restrict__ src, f16* __restrict__ dst,
                               int srcRows, int dstRows, int cols, int gshift) {
  int idx = blockIdx.x * blockDim.x + threadIdx.x;
  int total = dstRows << gshift;
  if (idx >= total) return;
  int row = idx >> gshift;
  int col = (idx & ((1 << gshift) - 1)) * 4;
  float4 v = make_float4(0.f, 0.f, 0.f, 0.f);
  if (row < srcRows) v = *(const float4*)&src[(size_t)row * cols + col];
  f16x4 o = {(f16)v.x, (f16)v.y, (f16)v.z, (f16)v.w};
  *(f16x4*)&dst[(size_t)row * cols + col] = o;
}

// ------------------------------ f16 GEMM -----------------------------------
// C[M,Ncols] = A * B^T, sync staging (global vec load -> ds_write), XOR
// swizzle on 16B chunks to keep ds_read_b128 conflict-free.
template <int BM, int TPB>
__global__ __launch_bounds__(TPB) void gemm_f16_kernel(
    const f16* __restrict__ A, const f16* __restrict__ Bm, f16* __restrict__ C,
    int K, int Ncols) {
  __shared__ f16 lA[BM * 32];
  __shared__ f16 lB[128 * 32];
  const int tid = threadIdx.x;
  const int w = tid >> 6, lane = tid & 63;
  const int wm = w >> 1, wn = w & 1;
  const int rowBase = blockIdx.y * BM;
  const int colBase = blockIdx.x * 128;
  const int lrow = lane & 15, lk = lane >> 4;
  f32x4 acc[4][4];
#pragma unroll
  for (int i = 0; i < 4; ++i)
#pragma unroll
    for (int j = 0; j < 4; ++j) acc[i][j] = (f32x4){0.f, 0.f, 0.f, 0.f};

  for (int kv = 0; kv < K; kv += 32) {
    f16x8 stA[(BM * 4) / TPB], stB[512 / TPB];
#pragma unroll
    for (int s = 0; s < (BM * 4) / TPB; ++s) {
      int q = s * TPB + tid;
      int r = q >> 2;
      int cs = (q & 3) ^ ((r >> 1) & 3);
      stA[s] = *(const f16x8*)(A + (size_t)(rowBase + r) * K + kv + cs * 8);
    }
#pragma unroll
    for (int s = 0; s < 512 / TPB; ++s) {
      int q = s * TPB + tid;
      int r = q >> 2;
      int cs = (q & 3) ^ ((r >> 1) & 3);
      stB[s] = *(const f16x8*)(Bm + (size_t)(colBase + r) * K + kv + cs * 8);
    }
#pragma unroll
    for (int s = 0; s < (BM * 4) / TPB; ++s)
      *(f16x8*)&lA[(size_t)(s * TPB + tid) * 8] = stA[s];
#pragma unroll
    for (int s = 0; s < 512 / TPB; ++s)
      *(f16x8*)&lB[(size_t)(s * TPB + tid) * 8] = stB[s];
    __syncthreads();
    f16x8 aF[4], bF[4];
#pragma unroll
    for (int i = 0; i < 4; ++i) {
      int ra = wm * 64 + i * 16 + lrow;
      aF[i] = *(const f16x8*)&lA[(ra * 4 + (lk ^ ((ra >> 1) & 3))) * 8];
      int rb = wn * 64 + i * 16 + lrow;
      bF[i] = *(const f16x8*)&lB[(rb * 4 + (lk ^ ((rb >> 1) & 3))) * 8];
    }
#pragma unroll
    for (int i = 0; i < 4; ++i)
#pragma unroll
      for (int j = 0; j < 4; ++j)
        acc[i][j] = __builtin_amdgcn_mfma_f32_16x16x32_f16(aF[i], bF[j], acc[i][j], 0, 0, 0);
    __syncthreads();
  }
  // C/D layout: col = lane&15, row = (lane>>4)*4 + reg
#pragma unroll
  for (int i = 0; i < 4; ++i) {
    int row0 = rowBase + wm * 64 + i * 16 + lk * 4;
#pragma unroll
    for (int j = 0; j < 4; ++j) {
      int col = colBase + wn * 64 + j * 16 + lrow;
#pragma unroll
      for (int rr = 0; rr < 4; ++rr)
        C[(size_t)(row0 + rr) * Ncols + col] = (f16)acc[i][j][rr];
    }
  }
}

// ------------------- attention coefficients a_src / a_dst ------------------
__global__ __launch_bounds__(256) void attn_coef_kernel(
    const f16* __restrict__ xw, const float* __restrict__ attS,
    const float* __restrict__ attD, float* __restrict__ aS, float* __restrict__ aD,
    int NH, int H) {
  int wg = blockIdx.x * 4 + (threadIdx.x >> 6);
  int lane = threadIdx.x & 63;
  if (wg >= NH) return;
  int h = wg & (H - 1);
  const f16x2 v = *(const f16x2*)&xw[(size_t)wg * 128 + lane * 2];
  const float2 s2 = *(const float2*)&attS[h * 128 + lane * 2];
  const float2 d2 = *(const float2*)&attD[h * 128 + lane * 2];
  float ps = (float)v[0] * s2.x + (float)v[1] * s2.y;
  float pd = (float)v[0] * d2.x + (float)v[1] * d2.y;
#pragma unroll
  for (int off = 32; off; off >>= 1) {
    ps += __shfl_xor(ps, off);
    pd += __shfl_xor(pd, off);
  }
  if (lane == 0) { aS[wg] = ps; aD[wg] = pd; }
}

// --------------------- layer-1 aggregation (per dst) -----------------------
// block = 4 waves = 4 heads, one dst per block. Within a wave: 2 edges per
// iteration (half = lane>>5 selects the edge, 32 lanes x f16x4 cover 128 ch),
// unrolled 4x -> 8 gathers in flight. OOB pair slots have wv=0 (alpha=0,
// src=0 -> harmless row-0 load). Epilogue: elu(acc+b1) -> f16 A2.
__global__ __launch_bounds__(256) void agg1_kernel(
    const int* __restrict__ row_ptr, const int* __restrict__ csr,
    const float* __restrict__ aS, const float* __restrict__ aD,
    const f16* __restrict__ xw, const float* __restrict__ bias,
    f16* __restrict__ A2) {
  const int dst = blockIdx.x;
  const int h = threadIdx.x >> 6, lane = threadIdx.x & 63;
  const int half = lane >> 5, lc = lane & 31;
  const int beg = row_ptr[dst], end = row_ptr[dst + 1];
  const float a_d = aD[dst * 4 + h];
  float den = 0.f;
  for (int i = beg + lane; i < end; i += 64) {
    int s = csr[i];
    float e = aS[s * 4 + h] + a_d;
    e = (e > 0.f) ? e : 0.2f * e;
    den += __expf(e);
  }
#pragma unroll
  for (int off = 32; off; off >>= 1) den += __shfl_xor(den, off);
  const float inv = 1.f / den;

  f32x4 acc = {0.f, 0.f, 0.f, 0.f};
  const f16* xrow = xw + h * 128 + lc * 4;
  for (int base = beg; base < end; base += 64) {
    int i = base + lane;
    float wv = 0.f;
    int s = 0;
    if (i < end) {
      s = csr[i];
      float e = aS[s * 4 + h] + a_d;
      e = (e > 0.f) ? e : 0.2f * e;
      wv = __expf(e);
    }
    int m = end - base;
    if (m > 64) m = 64;
    const int pairs = (m + 1) >> 1;
    int p = 0;
    for (; p + 4 <= pairs; p += 4) {
      float a[4];
      int sj[4];
      f16x4 v[4];
#pragma unroll
      for (int k = 0; k < 4; ++k) {
        int jj = (p + k) * 2 + half;
        a[k] = __shfl(wv, jj) * inv;
        sj[k] = __shfl(s, jj);
      }
#pragma unroll
      for (int k = 0; k < 4; ++k) v[k] = *(const f16x4*)&xrow[(size_t)sj[k] * 512];
#pragma unroll
      for (int k = 0; k < 4; ++k) {
        acc[0] = fmaf(a[k], (float)v[k][0], acc[0]);
        acc[1] = fmaf(a[k], (float)v[k][1], acc[1]);
        acc[2] = fmaf(a[k], (float)v[k][2], acc[2]);
        acc[3] = fmaf(a[k], (float)v[k][3], acc[3]);
      }
    }
    for (; p < pairs; ++p) {
      int jj = p * 2 + half;
      float a0 = __shfl(wv, jj) * inv;
      int sj0 = __shfl(s, jj);
      f16x4 v0 = *(const f16x4*)&xrow[(size_t)sj0 * 512];
      acc[0] = fmaf(a0, (float)v0[0], acc[0]);
      acc[1] = fmaf(a0, (float)v0[1], acc[1]);
      acc[2] = fmaf(a0, (float)v0[2], acc[2]);
      acc[3] = fmaf(a0, (float)v0[3], acc[3]);
    }
  }
#pragma unroll
  for (int k = 0; k < 4; ++k) acc[k] += __shfl_xor(acc[k], 32);
  if (half == 0) {
    const int c = h * 128 + lc * 4;
    f16x4 o;
#pragma unroll
    for (int k = 0; k < 4; ++k) {
      float vv = acc[k] + bias[c + k];
      vv = (vv > 0.f) ? vv : (__expf(vv) - 1.f);
      o[k] = (f16)vv;
    }
    *(f16x4*)&A2[(size_t)dst * 512 + c] = o;
  }
}

// ------------- layer-2 aggregation + ELU + fused classifier ----------------
// one wave per dst (H=1, C=128); block = 4 dst; same 2-edge x4-unroll layout.
__global__ __launch_bounds__(256) void agg2_kernel(
    const int* __restrict__ row_ptr, const int* __restrict__ csr,
    const float* __restrict__ aS, const float* __restrict__ aD,
    const f16* __restrict__ xw2, const float* __restrict__ b2,
    const float* __restrict__ Wc, const float* __restrict__ bc,
    float* __restrict__ out, int n) {
  const int dst = blockIdx.x * 4 + (threadIdx.x >> 6);
  const int lane = threadIdx.x & 63;
  const int half = lane >> 5, lc = lane & 31;
  if (dst >= n) return;
  const int beg = row_ptr[dst], end = row_ptr[dst + 1];
  const float a_d = aD[dst];
  float den = 0.f;
  for (int i = beg + lane; i < end; i += 64) {
    int s = csr[i];
    float e = aS[s] + a_d;
    e = (e > 0.f) ? e : 0.2f * e;
    den += __expf(e);
  }
#pragma unroll
  for (int off = 32; off; off >>= 1) den += __shfl_xor(den, off);
  const float inv = 1.f / den;

  f32x4 acc = {0.f, 0.f, 0.f, 0.f};
  const f16* xrow = xw2 + lc * 4;
  for (int base = beg; base < end; base += 64) {
    int i = base + lane;
    float wv = 0.f;
    int s = 0;
    if (i < end) {
      s = csr[i];
      float e = aS[s] + a_d;
      e = (e > 0.f) ? e : 0.2f * e;
      wv = __expf(e);
    }
    int m = end - base;
    if (m > 64) m = 64;
    const int pairs = (m + 1) >> 1;
    int p = 0;
    for (; p + 4 <= pairs; p += 4) {
      float a[4];
      int sj[4];
      f16x4 v[4];
#pragma unroll
      for (int k = 0; k < 4; ++k) {
        int jj = (p + k) * 2 + half;
        a[k] = __shfl(wv, jj) * inv;
        sj[k] = __shfl(s, jj);
      }
#pragma unroll
      for (int k = 0; k < 4; ++k) v[k] = *(const f16x4*)&xrow[(size_t)sj[k] * 128];
#pragma unroll
      for (int k = 0; k < 4; ++k) {
        acc[0] = fmaf(a[k], (float)v[k][0], acc[0]);
        acc[1] = fmaf(a[k], (float)v[k][1], acc[1]);
        acc[2] = fmaf(a[k], (float)v[k][2], acc[2]);
        acc[3] = fmaf(a[k], (float)v[k][3], acc[3]);
      }
    }
    for (; p < pairs; ++p) {
      int jj = p * 2 + half;
      float a0 = __shfl(wv, jj) * inv;
      int sj0 = __shfl(s, jj);
      f16x4 v0 = *(const f16x4*)&xrow[(size_t)sj0 * 128];
      acc[0] = fmaf(a0, (float)v0[0], acc[0]);
      acc[1] = fmaf(a0, (float)v0[1], acc[1]);
      acc[2] = fmaf(a0, (float)v0[2], acc[2]);
      acc[3] = fmaf(a0, (float)v0[3], acc[3]);
    }
  }
#pragma unroll
  for (int k = 0; k < 4; ++k) acc[k] += __shfl_xor(acc[k], 32);
  // ELU + classifier: each lane holds 4 channels c = lc*4..lc*4+3
  const int c = lc * 4;
  float l0 = 0.f, l1 = 0.f;
#pragma unroll
  for (int k = 0; k < 4; ++k) {
    float vv = acc[k] + b2[c + k];
    vv = (vv > 0.f) ? vv : (__expf(vv) - 1.f);
    l0 = fmaf(vv, Wc[c + k], l0);
    l1 = fmaf(vv, Wc[128 + c + k], l1);
  }
#pragma unroll
  for (int off = 16; off; off >>= 1) {
    l0 += __shfl_xor(l0, off);
    l1 += __shfl_xor(l1, off);
  }
  if (lane == 0) {
    out[dst * 2] = l0 + bc[0];
    out[dst * 2 + 1] = l1 + bc[1];
  }
}

// ---------------------------------------------------------------------------

extern "C" void kernel_launch(void* const* d_in, const int* in_sizes, int n_in,
                              void* d_out, int out_size, void* d_ws, size_t ws_size,
                              hipStream_t stream) {
  const float* x     = (const float*)d_in[0];
  const int*   ei    = (const int*)d_in[1];
  const float* W1    = (const float*)d_in[2];
  const float* att1s = (const float*)d_in[3];
  const float* att1d = (const float*)d_in[4];
  const float* b1    = (const float*)d_in[5];
  const float* W2    = (const float*)d_in[6];
  const float* att2s = (const float*)d_in[7];
  const float* att2d = (const float*)d_in[8];
  const float* b2    = (const float*)d_in[9];
  const float* Wc    = (const float*)d_in[10];
  const float* bc    = (const float*)d_in[11];
  float* out = (float*)d_out;

  const int N = in_sizes[0] / 256;
  const int E = in_sizes[1] / 2;
  const int EA = E + N;
  const int Mpad = (N + 127) & ~127;
  const int NB = (N + 255) / 256;

  char* base = (char*)d_ws;
  size_t off = 0;
  auto alloc = [&](size_t bytes) -> char* {
    char* p = base + off;
    off = (off + bytes + 255) & ~(size_t)255;
    return p;
  };
  f16* A1f  = (f16*)alloc((size_t)Mpad * 256 * sizeof(f16));   // x in f16
  f16* B1f  = (f16*)alloc((size_t)512 * 256 * sizeof(f16));    // W1 f16
  f16* xw1h = (f16*)alloc((size_t)Mpad * 512 * sizeof(f16));   // layer1 pre-agg
  f16* A2   = (f16*)alloc((size_t)Mpad * 512 * sizeof(f16));   // h = elu(agg1)
  f16* B2f  = (f16*)alloc((size_t)128 * 512 * sizeof(f16));    // W2 f16
  f16* xw2h = (f16*)alloc((size_t)Mpad * 128 * sizeof(f16));   // layer2 pre-agg
  float* aS1 = (float*)alloc((size_t)N * 4 * sizeof(float));
  float* aD1 = (float*)alloc((size_t)N * 4 * sizeof(float));
  float* aS2 = (float*)alloc((size_t)N * sizeof(float));
  float* aD2 = (float*)alloc((size_t)N * sizeof(float));
  int* deg     = (int*)alloc((size_t)N * sizeof(int));
  int* row_ptr = (int*)alloc((size_t)(N + 1) * sizeof(int));
  int* cursor  = (int*)alloc((size_t)N * sizeof(int));
  int* csr     = (int*)alloc((size_t)EA * sizeof(int));
  int* tmp     = (int*)alloc((size_t)N * sizeof(int));
  int* bsum    = (int*)alloc((size_t)NB * sizeof(int));
  int* boff    = (int*)alloc((size_t)NB * sizeof(int));
  int* flag    = (int*)alloc(256);
  (void)n_in; (void)out_size; (void)ws_size;

  hipMemsetAsync(deg, 0, (size_t)N * sizeof(int), stream);
  if (Mpad > N)  // zero A2 pad rows so GEMM2 pad outputs stay finite
    hipMemsetAsync(A2 + (size_t)N * 512, 0, (size_t)(Mpad - N) * 512 * sizeof(f16), stream);

  detect_i64_kernel<<<1, 64, 0, stream>>>(ei, flag);
  hist_kernel<<<(EA + 255) / 256, 256, 0, stream>>>(ei, E, N, flag, deg);
  scan1_kernel<<<NB, 256, 0, stream>>>(deg, tmp, bsum, N);
  scan2_kernel<<<1, 256, 0, stream>>>(bsum, boff, NB);
  scan3_kernel<<<NB, 256, 0, stream>>>(deg, tmp, boff, row_ptr, cursor, N);
  scatter_kernel<<<(EA + 255) / 256, 256, 0, stream>>>(ei, E, N, flag, cursor, csr);

  cvt_f16_kernel<<<(Mpad * 64 + 255) / 256, 256, 0, stream>>>(x, A1f, N, Mpad, 256, 6);
  cvt_f16_kernel<<<(512 * 64 + 255) / 256, 256, 0, stream>>>(W1, B1f, 512, 512, 256, 6);
  cvt_f16_kernel<<<(128 * 128 + 255) / 256, 256, 0, stream>>>(W2, B2f, 128, 128, 512, 7);

  dim3 g1(4, Mpad / 128);
  gemm_f16_kernel<128, 256><<<g1, 256, 0, stream>>>(A1f, B1f, xw1h, 256, 512);
  attn_coef_kernel<<<N, 256, 0, stream>>>(xw1h, att1s, att1d, aS1, aD1, N * 4, 4);
  agg1_kernel<<<N, 256, 0, stream>>>(row_ptr, csr, aS1, aD1, xw1h, b1, A2);

  dim3 g2(1, Mpad / 64);
  gemm_f16_kernel<64, 128><<<g2, 128, 0, stream>>>(A2, B2f, xw2h, 512, 128);
  attn_coef_kernel<<<(N + 3) / 4, 256, 0, stream>>>(xw2h, att2s, att2d, aS2, aD2, N, 1);
  agg2_kernel<<<(N + 3) / 4, 256, 0, stream>>>(row_ptr, csr, aS2, aD2, xw2h, b2, Wc, bc, out, N);
}